// Round 2
// baseline (359.454 us; speedup 1.0000x reference)
//
#include <hip/hip_runtime.h>
#include <cstdint>

#define N_ITER 64
#define N_CH 256
#define BATCH 4096
#define OUT_PLANE (BATCH * N_CH) /* 1048576 floats per output tensor */

// One wave (64 lanes) per batch row; lane l handles channels 4l..4l+3 as float4.
// Block = 256 threads = 4 rows. Grid = BATCH/4 = 1024 blocks.
//
// Math: the per-step int24 wrap never fires for this data (|prefix sums| < ~5e6
// << 2^23), so an int32 sum of rintf(x) reproduces the scan exactly. The
// PrecisionSplit, however, is computed by the reference in fp32: for negative y,
// y_u = y + 2^25 lands in [2^24, 2^25] where fp32 ulp=2; odd values are exact
// ties and round-half-even snaps them to the nearest multiple of 4:
//   y ≡ 1 (mod 4) -> u-1 ;  y ≡ 3 (mod 4) -> u+1   (else exact)
// We replicate that perturbation, then split: lo = u' & 0xFFF,
// hi = ((u'>>12) + 4096) & 8191) - 4096. Handles the u' = 2^25 corner (-> 0,0).
__device__ __forceinline__ void split_ref_fp32(int y, float& lo, float& hi) {
    uint32_t u;
    if (y >= 0) {
        u = (uint32_t)y;
    } else {
        u = (uint32_t)(y + 33554432); // y + 2^25
        int m = y & 3;                // two's-complement residue mod 4
        if (m == 1)      u -= 1u;     // tie rounds down to multiple of 4
        else if (m == 3) u += 1u;     // tie rounds up to multiple of 4
    }
    lo = (float)(u & 0xFFFu);
    int q = (int)(u >> 12);                   // in [0, 8192]
    hi = (float)(((q + 4096) & 8191) - 4096); // signed 13-bit wrap
}

__global__ __launch_bounds__(256) void i24sum_kernel(const float* __restrict__ x,
                                                     const float* __restrict__ s_init,
                                                     float* __restrict__ out) {
    const int tid  = threadIdx.x;
    const int lane = tid & 63;
    const int row  = blockIdx.x * 4 + (tid >> 6);

    // x row: [N_ITER][N_CH] floats = 4096 float4s; float4 index within row = i*64 + lane
    const float4* xr = reinterpret_cast<const float4*>(x) + (size_t)row * (N_ITER * N_CH / 4);
    const float4  s4 = reinterpret_cast<const float4*>(s_init)[lane];

    int ax = (int)rintf(s4.x);
    int ay = (int)rintf(s4.y);
    int az = (int)rintf(s4.z);
    int aw = (int)rintf(s4.w);

#pragma unroll 16
    for (int i = 0; i < N_ITER; ++i) {
        float4 v = xr[i * (N_CH / 4) + lane];
        ax += (int)rintf(v.x);  // rintf = round-half-even, matches jnp.round
        ay += (int)rintf(v.y);
        az += (int)rintf(v.z);
        aw += (int)rintf(v.w);
    }

    // sign-extend to int24 domain (identity for this data — no wrap occurs)
    ax = (ax << 8) >> 8;
    ay = (ay << 8) >> 8;
    az = (az << 8) >> 8;
    aw = (aw << 8) >> 8;

    float4 lo4, hi4;
    split_ref_fp32(ax, lo4.x, hi4.x);
    split_ref_fp32(ay, lo4.y, hi4.y);
    split_ref_fp32(az, lo4.z, hi4.z);
    split_ref_fp32(aw, lo4.w, hi4.w);

    const int ovec = (row * N_CH) / 4 + lane;  // float4 index
    reinterpret_cast<float4*>(out)[ovec] = lo4;
    reinterpret_cast<float4*>(out + OUT_PLANE)[ovec] = hi4;
}

extern "C" void kernel_launch(void* const* d_in, const int* in_sizes, int n_in,
                              void* d_out, int out_size, void* d_ws, size_t ws_size,
                              hipStream_t stream) {
    const float* x      = (const float*)d_in[0];
    const float* s_init = (const float*)d_in[1];
    float*       out    = (float*)d_out;

    dim3 grid(BATCH / 4);
    dim3 block(256);
    i24sum_kernel<<<grid, block, 0, stream>>>(x, s_init, out);
}

// Round 4
// 335.297 us; speedup vs baseline: 1.0720x; 1.0720x over previous
//
#include <hip/hip_runtime.h>
#include <cstdint>

#define N_ITER 64
#define N_CH 256
#define BATCH 4096
#define OUT_PLANE (BATCH * N_CH) /* 1048576 floats per output tensor */

typedef float v4f __attribute__((ext_vector_type(4)));
typedef int   v4i __attribute__((ext_vector_type(4)));
typedef float v2f __attribute__((ext_vector_type(2)));

// Exact replication of the fp32 reference's PrecisionSplit.
// For negative y, y_u = y + 2^25 lands where fp32 ulp = 2; odd y is an exact
// tie and round-half-even snaps to the nearest multiple of 4:
//   y ≡ 1 (mod 4) -> u-1 ;  y ≡ 3 (mod 4) -> u+1   (else exact)
// Then lo = u' & 0xFFF, hi = ((u'>>12 + 4096) & 8191) - 4096 (exact in fp32,
// including the u' = 2^25 corner -> (0,0)). Returns {lo, hi}.
__device__ __forceinline__ v2f split_ref_fp32(int y) {
    uint32_t u;
    if (y >= 0) {
        u = (uint32_t)y;
    } else {
        u = (uint32_t)(y + 33554432); // y + 2^25
        int m = y & 3;
        if (m == 1)      u -= 1u;
        else if (m == 3) u += 1u;
    }
    v2f r;
    r.x = (float)(u & 0xFFFu);
    int q = (int)(u >> 12);
    r.y = (float)(((q + 4096) & 8191) - 4096);
    return r;
}

// One block (4 waves) per batch row. Wave w sums iterations 16w..16w+15;
// lane l owns channels 4l..4l+3 (v4f loads, 1 KiB per wave per instruction,
// fully coalesced). Integer adds are associative, so splitting the 64-step
// scan across waves is exact. LDS reduction (4 KiB), wave 0 does the split.
__global__ __launch_bounds__(256) void i24sum_kernel(const float* __restrict__ x,
                                                     const float* __restrict__ s_init,
                                                     float* __restrict__ out) {
    const int tid  = threadIdx.x;
    const int lane = tid & 63;
    const int wave = tid >> 6;
    const int row  = blockIdx.x;

    const v4f* xr = reinterpret_cast<const v4f*>(x) + (size_t)row * (N_ITER * N_CH / 4);

    v4i acc = (v4i)0;
#pragma unroll
    for (int k = 0; k < 16; ++k) {
        const int i = (wave << 4) + k;
        v4f v = __builtin_nontemporal_load(xr + i * (N_CH / 4) + lane);
        acc.x += (int)rintf(v.x);  // rintf = round-half-even, matches jnp.round
        acc.y += (int)rintf(v.y);
        acc.z += (int)rintf(v.z);
        acc.w += (int)rintf(v.w);
    }

    __shared__ v4i part[4][64];
    part[wave][lane] = acc;
    __syncthreads();

    if (wave == 0) {
        const v4f s4 = reinterpret_cast<const v4f*>(s_init)[lane];
        v4i t = part[0][lane];
        t += part[1][lane];
        t += part[2][lane];
        t += part[3][lane];
        t.x += (int)rintf(s4.x);
        t.y += (int)rintf(s4.y);
        t.z += (int)rintf(s4.z);
        t.w += (int)rintf(s4.w);

        // sign-extend to int24 domain (identity for this data — no wrap occurs,
        // |sums| << 2^23; kept for semantic fidelity to the mod-2^24 scan)
        t.x = (t.x << 8) >> 8;
        t.y = (t.y << 8) >> 8;
        t.z = (t.z << 8) >> 8;
        t.w = (t.w << 8) >> 8;

        const v2f sx = split_ref_fp32(t.x);
        const v2f sy = split_ref_fp32(t.y);
        const v2f sz = split_ref_fp32(t.z);
        const v2f sw = split_ref_fp32(t.w);

        v4f lo4, hi4;
        lo4.x = sx.x; hi4.x = sx.y;
        lo4.y = sy.x; hi4.y = sy.y;
        lo4.z = sz.x; hi4.z = sz.y;
        lo4.w = sw.x; hi4.w = sw.y;

        const int ovec = row * (N_CH / 4) + lane;  // v4f index within plane
        reinterpret_cast<v4f*>(out)[ovec] = lo4;
        reinterpret_cast<v4f*>(out + OUT_PLANE)[ovec] = hi4;
    }
}

extern "C" void kernel_launch(void* const* d_in, const int* in_sizes, int n_in,
                              void* d_out, int out_size, void* d_ws, size_t ws_size,
                              hipStream_t stream) {
    const float* x      = (const float*)d_in[0];
    const float* s_init = (const float*)d_in[1];
    float*       out    = (float*)d_out;

    dim3 grid(BATCH);   // one block per row: 4096 blocks, 16k waves, 64/CU ask
    dim3 block(256);
    i24sum_kernel<<<grid, block, 0, stream>>>(x, s_init, out);
}